// Round 8
// baseline (11538.889 us; speedup 1.0000x reference)
//
#include <hip/hip_runtime.h>
#include <stdint.h>

#define D_ 1024
#define H_ 16
#define HD_ 64
#define FF_ 4096
#define T_ 4096
#define TC_ 4097
#define CHUNK_ 128
#define NCH_ 33
#define LAYERS_ 8
#define NB_ 1024

// ws layout (floats) — all inside the proven-safe [0, 80928) float range
#define WS_QKV 0          // [3072]
#define WS_GU 3072        // [8192]
#define WS_HID 11264      // [1024]
#define WS_PART 12288     // [16*33*66 = 34848], ends 47136
#define WS_BAR 47136      // barrier flags (uint): [0..NB_) flags, gen at uint idx 1040
#define GEN_IDX 1040
#define BAR_UINTS 1056    // memset span

#define SPIN_BOUND 1000000

static constexpr float SCALE_ = 0.49497474683058327f; // 1.4/sqrt(8)
static constexpr float EPS_ = 1e-5f;

struct Params {
    const float* kc[LAYERS_];
    const float* vc[LAYERS_];
    const float* embed; const float* ln1; const float* ln2; const float* nw;
    const float* Wq; const float* Wk; const float* Wv; const float* Wo;
    const float* Wg; const float* Wu; const float* Wd;
    const int* pos;
    float* out;
    float* accQKV; float* accGU; float* hid; float* part;
    unsigned* bar;
};

__device__ __forceinline__ float wave_sum(float v) {
    #pragma unroll
    for (int off = 32; off; off >>= 1) v += __shfl_down(v, off, 64);
    return v;
}
__device__ __forceinline__ float wave_max(float v) {
    #pragma unroll
    for (int off = 32; off; off >>= 1) v = fmaxf(v, __shfl_down(v, off, 64));
    return v;
}

// ---- RMW-free grid barrier (bounded spins; flags in proven ws range) ----
// Arrivals release-store tgt to own flag; block 0 acquire-polls all flags then
// release-stores gen=tgt; spinners acquire-poll gen. Monotonic; memset 0 per launch.
__device__ __forceinline__ void gbar(unsigned* bar, int b, int t, unsigned tgt) {
    __threadfence();
    __syncthreads();
    if (b == 0) {
        for (int idx = t; idx < NB_; idx += 256) {
            if (idx == 0) continue;
            int guard = 0;
            while (__hip_atomic_load(&bar[idx], __ATOMIC_ACQUIRE, __HIP_MEMORY_SCOPE_AGENT) < tgt) {
                __builtin_amdgcn_s_sleep(2);
                if (++guard > SPIN_BOUND) break;   // fail visibly, never hang
            }
        }
        __syncthreads();
        if (t == 0)
            __hip_atomic_store(&bar[GEN_IDX], tgt, __ATOMIC_RELEASE, __HIP_MEMORY_SCOPE_AGENT);
        __syncthreads();
    } else {
        if (t == 0) {
            __hip_atomic_store(&bar[b], tgt, __ATOMIC_RELEASE, __HIP_MEMORY_SCOPE_AGENT);
            int guard = 0;
            while (__hip_atomic_load(&bar[GEN_IDX], __ATOMIC_ACQUIRE, __HIP_MEMORY_SCOPE_AGENT) < tgt) {
                __builtin_amdgcn_s_sleep(2);
                if (++guard > SPIN_BOUND) break;
            }
        }
        __syncthreads();
    }
}

// rms(hid)*lnw -> hn[1024]
__device__ __forceinline__ void rms_to_sm(const float* __restrict__ hid,
                                          const float* __restrict__ lnw,
                                          float* hn, float* wred, int t)
{
    float4 hv = ((const float4*)hid)[t];
    float ssq = hv.x*hv.x + hv.y*hv.y + hv.z*hv.z + hv.w*hv.w;
    ssq = wave_sum(ssq);
    if ((t & 63) == 0) wred[t >> 6] = ssq;
    __syncthreads();
    float rms = rsqrtf((wred[0] + wred[1] + wred[2] + wred[3]) * (1.0f / D_) + EPS_);
    float4 lw = ((const float4*)lnw)[t];
    hn[4*t+0] = hv.x * rms * lw.x;
    hn[4*t+1] = hv.y * rms * lw.y;
    hn[4*t+2] = hv.z * rms * lw.z;
    hn[4*t+3] = hv.w * rms * lw.w;
    __syncthreads();
}

// RT-row x 64-col gemv tile: dst[colbase..+64) += scale * (hsrc[rows] @ W-tile)
template<int RT>
__device__ __forceinline__ void gemv_tile(const float* __restrict__ hsrc,
                                          const float* __restrict__ W, int ncols,
                                          int rowbase, int colbase, float scale,
                                          float* __restrict__ dst, float4* red4, int t)
{
    constexpr int RPG = RT / 16;
    int c4 = t & 15, rg = t >> 4;
    int row0 = rowbase + rg * RPG;
    const float* Wp = W + (size_t)row0 * ncols + colbase + c4 * 4;
    float4 acc = make_float4(0.f, 0.f, 0.f, 0.f);
    #pragma unroll
    for (int r = 0; r < RPG; ++r) {
        float hs = hsrc[row0 + r];
        float4 w4 = *(const float4*)(Wp + (size_t)r * ncols);
        acc.x += hs*w4.x; acc.y += hs*w4.y; acc.z += hs*w4.z; acc.w += hs*w4.w;
    }
    red4[t] = acc;
    __syncthreads();
    if (t < 16) {
        float4 s = red4[t];
        #pragma unroll
        for (int g = 1; g < 16; ++g) {
            float4 r4 = red4[t + 16*g];
            s.x += r4.x; s.y += r4.y; s.z += r4.z; s.w += r4.w;
        }
        float* d = dst + colbase + t*4;
        atomicAdd(d+0, scale*s.x);
        atomicAdd(d+1, scale*s.y);
        atomicAdd(d+2, scale*s.z);
        atomicAdd(d+3, scale*s.w);
    }
    __syncthreads();
}

__launch_bounds__(256, 4)
__global__ void k_model(Params p)
{
    int t = threadIdx.x;
    int b = blockIdx.x;
    __shared__ float sm[2080];            // 8.3 KB
    float* hn    = sm;                    // [1024]
    float4* red4 = (float4*)(sm + 1024);  // [256] float4
    float* wred  = sm + 2048;             // [4]
    unsigned* bar = p.bar;
    unsigned kb = 0;

    // ---- init ----
    if (b == 0)      ((float4*)p.hid)[t] = ((const float4*)p.embed)[t];
    else if (b == 1) for (int i = t; i < 3072; i += 256) p.accQKV[i] = 0.f;
    else if (b == 2) for (int i = t; i < 2*FF_; i += 256) p.accGU[i] = 0.f;
    gbar(bar, b, t, ++kb);

    for (int L = 0; L < LAYERS_; ++L) {
        // ---- phase 1: QKV gemv (3 mats x 16 rowtiles x 16 coltiles = 768 tiles) ----
        if (b < 768) {
            rms_to_sm(p.hid, p.ln1 + L*D_, hn, wred, t);
            int mat = b >> 8, rem = b & 255, rt = rem >> 4, ct = rem & 15;
            const float* W = (mat == 0 ? p.Wq : mat == 1 ? p.Wk : p.Wv) + (size_t)L*D_*D_;
            gemv_tile<64>(hn, W, D_, rt*64, ct*64, 1.f, p.accQKV + mat*D_, red4, t);
        }
        gbar(bar, b, t, ++kb);

        // ---- phase 2: attention (33 chunks x 16 heads = 528 tiles) + f32 KV copy ----
        if (b < NCH_ * H_) {
            float* qr = sm;          // [64]
            float* kr = sm + 64;     // [64]
            float* sc = sm + 128;    // [128]
            float* wr2 = sm + 256;   // [8]
            float* red = sm + 264;   // [256]
            int c = b % NCH_, h = b / NCH_;
            const float* kcache = p.kc[L];
            const float* vcache = p.vc[L];
            float* kco = p.out + 1024 + (size_t)L * 2 * ((size_t)H_*TC_*HD_);
            float* vco = kco + (size_t)H_*TC_*HD_;
            if (t < 32) {
                float pos = (float)(*p.pos);
                float inv = expf(-(float)t * (9.210340371976184f / 32.0f));
                float ang = pos * inv;
                float cs = cosf(ang), sn = sinf(ang);
                float q1 = p.accQKV[h*64 + t], q2 = p.accQKV[h*64 + t + 32];
                qr[t] = q1*cs - q2*sn; qr[t+32] = q1*sn + q2*cs;
                float k1 = p.accQKV[1024 + h*64 + t], k2 = p.accQKV[1024 + h*64 + t + 32];
                kr[t] = k1*cs - k2*sn; kr[t+32] = k1*sn + k2*cs;
            }
            __syncthreads();
            int kstart = c * CHUNK_;
            int nk = min(CHUNK_, TC_ - kstart);
            // pass A: scores (16 lanes/key, float4) + f32 K copy
            int dsub = (t & 15) * 4;
            float4 qv = *(const float4*)&qr[dsub];
            for (int kl = (t >> 4); kl < nk; kl += 16) {
                int key = kstart + kl;
                float4 kv;
                if (key < T_) kv = *(const float4*)(kcache + ((size_t)h*T_ + key)*HD_ + dsub);
                else          kv = *(const float4*)&kr[dsub];
                float pd = qv.x*kv.x + qv.y*kv.y + qv.z*kv.z + qv.w*kv.w;
                pd += __shfl_down(pd, 8, 16);
                pd += __shfl_down(pd, 4, 16);
                pd += __shfl_down(pd, 2, 16);
                pd += __shfl_down(pd, 1, 16);
                if ((t & 15) == 0) sc[kl] = pd * 0.125f;
                *(float4*)(kco + ((size_t)h*TC_ + key)*HD_ + dsub) = kv;
            }
            __syncthreads();
            // parallel chunk softmax (nk <= 128 <= 256)
            float m = (t < nk) ? sc[t] : -INFINITY;
            m = wave_max(m);
            if ((t & 63) == 0) wr2[t >> 6] = m;
            __syncthreads();
            m = fmaxf(fmaxf(wr2[0], wr2[1]), fmaxf(wr2[2], wr2[3]));
            float e = 0.f;
            if (t < nk) { e = __expf(sc[t] - m); sc[t] = e; }
            float s = wave_sum(e);
            if ((t & 63) == 0) wr2[4 + (t >> 6)] = s;
            __syncthreads();
            float* pb = p.part + ((size_t)h*NCH_ + c)*66;
            if (t == 0) { pb[0] = m; pb[1] = wr2[4]+wr2[5]+wr2[6]+wr2[7]; }
            __syncthreads();
            // pass B: weighted V (dim = t&63, 4 key-groups of 32) + f32 V copy
            int dim = t & 63, kg = t >> 6;
            float acc = 0.f;
            int klend = min(nk, kg*32 + 32);
            for (int kl = kg*32; kl < klend; ++kl) {
                int key = kstart + kl;
                float v;
                if (key < T_) v = vcache[((size_t)h*T_ + key)*HD_ + dim];
                else          v = p.accQKV[2048 + h*64 + dim];
                acc += sc[kl] * v;
                vco[((size_t)h*TC_ + key)*HD_ + dim] = v;
            }
            red[t] = acc;
            __syncthreads();
            if (t < 64) pb[2 + t] = red[t] + red[t+64] + red[t+128] + red[t+192];
        }
        gbar(bar, b, t, ++kb);

        // ---- phase 3: combine + Wo (16 heads x 16 coltiles = 256 tiles); zero accums ----
        if (b < 256) {
            float* oh = sm;  // [64]
            int h = b >> 4, ct = b & 15;
            if (t < 64) {
                const float* pb = p.part + (size_t)h * NCH_ * 66;
                float M = -INFINITY;
                for (int c = 0; c < NCH_; ++c) M = fmaxf(M, pb[c*66]);
                float S = 0.f, O = 0.f;
                for (int c = 0; c < NCH_; ++c) {
                    float e = __expf(pb[c*66] - M);
                    S += pb[c*66 + 1] * e;
                    O += pb[c*66 + 2 + t] * e;
                }
                oh[t] = O / S;
            }
            __syncthreads();
            gemv_tile<64>(oh - h*64, p.Wo + (size_t)L*D_*D_, D_, h*64, ct*64, SCALE_, p.hid, red4, t);
        } else if (b == 256) {
            for (int i = t; i < 2*FF_; i += 256) p.accGU[i] = 0.f;
        } else if (b == 257) {
            for (int i = t; i < 3072; i += 256) p.accQKV[i] = 0.f;
        }
        gbar(bar, b, t, ++kb);

        // ---- phase 4: G/U gemv (2 mats x 8 rowtiles(128) x 64 coltiles = 1024 tiles) ----
        {
            rms_to_sm(p.hid, p.ln2 + L*D_, hn, wred, t);
            int mat = b >> 9, rem = b & 511, rt = rem >> 6, ct = rem & 63;
            const float* W = (mat ? p.Wu : p.Wg) + (size_t)L*D_*FF_;
            gemv_tile<128>(hn, W, FF_, rt*128, ct*64, 1.f, p.accGU + mat*FF_, red4, t);
        }
        gbar(bar, b, t, ++kb);

        // ---- phase 5: down gemv (64 rowtiles(64) x 16 coltiles = 1024 tiles) ----
        {
            float* act = sm;  // [64]
            int rt = b >> 4, ct = b & 15;
            int rowbase = rt * 64;
            if (t < 64) {
                float g = p.accGU[rowbase + t];
                float u = p.accGU[FF_ + rowbase + t];
                act[t] = g / (1.f + __expf(-g)) * u;
            }
            __syncthreads();
            gemv_tile<64>(act - rowbase, p.Wd + (size_t)L*FF_*D_, D_, rowbase, ct*64, SCALE_, p.hid, red4, t);
        }
        gbar(bar, b, t, ++kb);
    }

    // ---- final RMS norm ----
    if (b == 0) {
        float4 hv = ((const float4*)p.hid)[t];
        float ssq = hv.x*hv.x + hv.y*hv.y + hv.z*hv.z + hv.w*hv.w;
        ssq = wave_sum(ssq);
        if ((t & 63) == 0) wred[t >> 6] = ssq;
        __syncthreads();
        float rms = rsqrtf((wred[0] + wred[1] + wred[2] + wred[3]) * (1.0f / D_) + EPS_);
        float4 w = ((const float4*)p.nw)[t];
        float4 ob;
        ob.x = hv.x * rms * w.x; ob.y = hv.y * rms * w.y;
        ob.z = hv.z * rms * w.z; ob.w = hv.w * rms * w.w;
        ((float4*)p.out)[t] = ob;
    }
}

// ==================== fallback multi-kernel path (proven) ====================

__global__ void k_init(const float* __restrict__ embed, float* __restrict__ hid,
                       float* __restrict__ accQKV) {
    int t = threadIdx.x;
    ((float4*)hid)[t] = ((const float4*)embed)[t];
    for (int i = t; i < 3072; i += 256) accQKV[i] = 0.f;
}

template<int NCOLS>
__global__ void k_rms_gemv(const float* __restrict__ hidden, const float* __restrict__ lnw,
                           const float* __restrict__ W0, const float* __restrict__ W1,
                           const float* __restrict__ W2, float* __restrict__ out)
{
    int t = threadIdx.x;
    __shared__ float hn[D_];
    __shared__ float wred[4];
    __shared__ float4 red4s[256];
    rms_to_sm(hidden, lnw, hn, wred, t);
    const float* W = (blockIdx.z == 0) ? W0 : (blockIdx.z == 1 ? W1 : W2);
    gemv_tile<64>(hn, W, NCOLS, blockIdx.y*64, blockIdx.x*64, 1.f,
                  out + (size_t)blockIdx.z * NCOLS, red4s, t);
}

__global__ void k_attn_f(const float* __restrict__ kcache, const float* __restrict__ vcache,
                         const float* __restrict__ qkv, const int* __restrict__ posp,
                         float* __restrict__ kc_out, float* __restrict__ vc_out,
                         float* __restrict__ part)
{
    int c = blockIdx.x, h = blockIdx.y, t = threadIdx.x;
    __shared__ float qr[64], kr[64], sc[CHUNK_], red[256], wr2[8];
    if (t < 32) {
        float pos = (float)(*posp);
        float inv = expf(-(float)t * (9.210340371976184f / 32.0f));
        float ang = pos * inv;
        float cs = cosf(ang), sn = sinf(ang);
        float q1 = qkv[h*64 + t], q2 = qkv[h*64 + t + 32];
        qr[t] = q1*cs - q2*sn; qr[t+32] = q1*sn + q2*cs;
        float k1 = qkv[1024 + h*64 + t], k2 = qkv[1024 + h*64 + t + 32];
        kr[t] = k1*cs - k2*sn; kr[t+32] = k1*sn + k2*cs;
    }
    __syncthreads();
    int kstart = c * CHUNK_;
    int nk = min(CHUNK_, TC_ - kstart);
    int dsub = (t & 15) * 4;
    float4 qv = *(const float4*)&qr[dsub];
    for (int kl = (t >> 4); kl < nk; kl += 16) {
        int key = kstart + kl;
        float4 kv;
        if (key < T_) kv = *(const float4*)(kcache + ((size_t)h*T_ + key)*HD_ + dsub);
        else          kv = *(const float4*)&kr[dsub];
        float pd = qv.x*kv.x + qv.y*kv.y + qv.z*kv.z + qv.w*kv.w;
        pd += __shfl_down(pd, 8, 16);
        pd += __shfl_down(pd, 4, 16);
        pd += __shfl_down(pd, 2, 16);
        pd += __shfl_down(pd, 1, 16);
        if ((t & 15) == 0) sc[kl] = pd * 0.125f;
        *(float4*)(kc_out + ((size_t)h*TC_ + key)*HD_ + dsub) = kv;
    }
    __syncthreads();
    float m = (t < nk) ? sc[t] : -INFINITY;
    m = wave_max(m);
    if ((t & 63) == 0) wr2[t >> 6] = m;
    __syncthreads();
    m = fmaxf(fmaxf(wr2[0], wr2[1]), fmaxf(wr2[2], wr2[3]));
    float e = 0.f;
    if (t < nk) { e = __expf(sc[t] - m); sc[t] = e; }
    float s = wave_sum(e);
    if ((t & 63) == 0) wr2[4 + (t >> 6)] = s;
    __syncthreads();
    float* pb = part + ((size_t)h*NCH_ + c)*66;
    if (t == 0) { pb[0] = m; pb[1] = wr2[4]+wr2[5]+wr2[6]+wr2[7]; }
    __syncthreads();
    int dim = t & 63, kg = t >> 6;
    float acc = 0.f;
    int klend = min(nk, kg*32 + 32);
    for (int kl = kg*32; kl < klend; ++kl) {
        int key = kstart + kl;
        float v;
        if (key < T_) v = vcache[((size_t)h*T_ + key)*HD_ + dim];
        else          v = qkv[2048 + h*64 + dim];
        acc += sc[kl] * v;
        vc_out[((size_t)h*TC_ + key)*HD_ + dim] = v;
    }
    red[t] = acc;
    __syncthreads();
    if (t < 64) pb[2 + t] = red[t] + red[t+64] + red[t+128] + red[t+192];
}

__global__ void k_wo(const float* __restrict__ part, const float* __restrict__ Wo,
                     float* __restrict__ hidden, float* __restrict__ accGU)
{
    int h = blockIdx.y, t = threadIdx.x;
    if (blockIdx.x == 0 && blockIdx.y == 0)
        for (int i = t; i < 2*FF_; i += 256) accGU[i] = 0.f;
    __shared__ float oh[64];
    __shared__ float4 red4s[256];
    if (t < 64) {
        const float* pb = part + (size_t)h * NCH_ * 66;
        float M = -INFINITY;
        for (int c = 0; c < NCH_; ++c) M = fmaxf(M, pb[c*66]);
        float S = 0.f, O = 0.f;
        for (int c = 0; c < NCH_; ++c) {
            float e = __expf(pb[c*66] - M);
            S += pb[c*66 + 1] * e;
            O += pb[c*66 + 2 + t] * e;
        }
        oh[t] = O / S;
    }
    __syncthreads();
    gemv_tile<64>(oh - h*64, Wo, D_, h*64, blockIdx.x*64, SCALE_, hidden, red4s, t);
}

__global__ void k_down(const float* __restrict__ gu, const float* __restrict__ Wd,
                       float* __restrict__ hidden, float* __restrict__ accQKV)
{
    int t = threadIdx.x;
    if (blockIdx.x == 0 && blockIdx.y == 0)
        for (int i = t; i < 3072; i += 256) accQKV[i] = 0.f;
    __shared__ float act[64];
    __shared__ float4 red4s[256];
    int rowbase = blockIdx.y * 64;
    if (t < 64) {
        float g = gu[rowbase + t];
        float u = gu[FF_ + rowbase + t];
        act[t] = g / (1.f + __expf(-g)) * u;
    }
    __syncthreads();
    gemv_tile<64>(act - rowbase, Wd, D_, rowbase, blockIdx.x*64, SCALE_, hidden, red4s, t);
}

__global__ void k_final(const float* __restrict__ hidden, const float* __restrict__ nw,
                        float* __restrict__ out)
{
    int t = threadIdx.x;
    __shared__ float wred[4];
    float4 hv = ((const float4*)hidden)[t];
    float ssq = hv.x*hv.x + hv.y*hv.y + hv.z*hv.z + hv.w*hv.w;
    ssq = wave_sum(ssq);
    if ((t & 63) == 0) wred[t >> 6] = ssq;
    __syncthreads();
    float rms = rsqrtf((wred[0] + wred[1] + wred[2] + wred[3]) * (1.0f / D_) + EPS_);
    float4 w = ((const float4*)nw)[t];
    float4 ob;
    ob.x = hv.x * rms * w.x; ob.y = hv.y * rms * w.y;
    ob.z = hv.z * rms * w.z; ob.w = hv.w * rms * w.w;
    ((float4*)out)[t] = ob;
}

// role indices: 0 embed, 1+2i k_i, 2+2i v_i, 17 ln1, 18 ln2, 19 norm,
//               20 Wq, 21 Wk, 22 Wv, 23 Wo, 24 Wg, 25 Wu, 26 Wd, 27 pos
static const int ROLE_SIZES[28] = {
    1024,
    4194304,4194304,4194304,4194304,4194304,4194304,4194304,4194304,
    4194304,4194304,4194304,4194304,4194304,4194304,4194304,4194304,
    8192, 8192, 1024,
    8388608, 8388608, 8388608, 8388608,
    33554432, 33554432, 33554432,
    1
};

extern "C" void kernel_launch(void* const* d_in, const int* in_sizes, int n_in,
                              void* d_out, int out_size, void* d_ws, size_t ws_size,
                              hipStream_t stream)
{
    int perm[28];
    bool matched = false;
    auto try_perm = [&](const int* cand) {
        if (matched) return;
        for (int r = 0; r < 28; ++r)
            if (in_sizes[cand[r]] != ROLE_SIZES[r]) return;
        for (int r = 0; r < 28; ++r) perm[r] = cand[r];
        matched = true;
    };
    {   int c[28]; for (int r = 0; r < 28; ++r) c[r] = r; try_perm(c); }  // C0 dict (matched)
    {   int c[28];
        c[0]=0; c[27]=1;
        for (int i = 0; i < 8; ++i) { c[1+2*i]=2+2*i; c[2+2*i]=3+2*i; }
        c[17]=18; c[18]=19; c[19]=20;
        c[20]=21; c[21]=22; c[22]=23; c[23]=24; c[24]=25; c[25]=26; c[26]=27;
        try_perm(c); }                                                    // C1 signature
    if (!matched) { for (int r = 0; r < 28; ++r) perm[r] = r; }

    Params prm;
    prm.embed = (const float*)d_in[perm[0]];
    for (int i = 0; i < LAYERS_; ++i) {
        prm.kc[i] = (const float*)d_in[perm[1+2*i]];
        prm.vc[i] = (const float*)d_in[perm[2+2*i]];
    }
    prm.ln1 = (const float*)d_in[perm[17]];
    prm.ln2 = (const float*)d_in[perm[18]];
    prm.nw  = (const float*)d_in[perm[19]];
    prm.Wq  = (const float*)d_in[perm[20]];
    prm.Wk  = (const float*)d_in[perm[21]];
    prm.Wv  = (const float*)d_in[perm[22]];
    prm.Wo  = (const float*)d_in[perm[23]];
    prm.Wg  = (const float*)d_in[perm[24]];
    prm.Wu  = (const float*)d_in[perm[25]];
    prm.Wd  = (const float*)d_in[perm[26]];
    prm.pos = (const int*)d_in[perm[27]];

    float* ws = (float*)d_ws;
    prm.out    = (float*)d_out;
    prm.accQKV = ws + WS_QKV;
    prm.accGU  = ws + WS_GU;
    prm.hid    = ws + WS_HID;
    prm.part   = ws + WS_PART;
    prm.bar    = (unsigned*)(ws + WS_BAR);

    (void)out_size; (void)n_in;

    // coop path requires bar region in-bounds: needs (47136 + 1056) floats ~ 193KB
    bool coop_ok = (ws_size >= (size_t)(WS_BAR + BAR_UINTS) * sizeof(float) + 1024);

    if (coop_ok) {
        hipMemsetAsync((void*)prm.bar, 0, BAR_UINTS * sizeof(unsigned), stream);
        void* kargs[] = { (void*)&prm };
        hipError_t err = hipLaunchCooperativeKernel((const void*)k_model, dim3(NB_), dim3(256),
                                                    kargs, 0, stream);
        if (err == hipSuccess) return;
    }

    // -------- fallback: proven multi-kernel path --------
    k_init<<<1, 256, 0, stream>>>(prm.embed, prm.hid, prm.accQKV);
    const size_t KVSZ = (size_t)H_ * TC_ * HD_;
    for (int i = 0; i < LAYERS_; ++i) {
        float* kco = prm.out + 1024 + (size_t)i * 2 * KVSZ;
        float* vco = kco + KVSZ;
        k_rms_gemv<D_><<<dim3(16, 16, 3), 256, 0, stream>>>(
            prm.hid, prm.ln1 + i*D_,
            prm.Wq + (size_t)i*D_*D_, prm.Wk + (size_t)i*D_*D_, prm.Wv + (size_t)i*D_*D_,
            prm.accQKV);
        k_attn_f<<<dim3(NCH_, H_), 256, 0, stream>>>(prm.kc[i], prm.vc[i], prm.accQKV, prm.pos,
                                                     kco, vco, prm.part);
        k_wo<<<dim3(16, 16), 256, 0, stream>>>(prm.part, prm.Wo + (size_t)i*D_*D_, prm.hid, prm.accGU);
        k_rms_gemv<FF_><<<dim3(64, 16, 2), 256, 0, stream>>>(
            prm.hid, prm.ln2 + i*D_,
            prm.Wg + (size_t)i*D_*FF_, prm.Wu + (size_t)i*D_*FF_, nullptr,
            prm.accGU);
        k_down<<<dim3(16, 64), 256, 0, stream>>>(prm.accGU, prm.Wd + (size_t)i*FF_*D_, prm.hid, prm.accQKV);
    }
    k_final<<<1, 256, 0, stream>>>(prm.hid, prm.nw, prm.out);
}

// Round 9
// 473.119 us; speedup vs baseline: 24.3890x; 24.3890x over previous
//
#include <hip/hip_runtime.h>
#include <stdint.h>

#define D_ 1024
#define H_ 16
#define HD_ 64
#define FF_ 4096
#define T_ 4096
#define TC_ 4097
#define CHUNK_ 64
#define NCH_ 65
#define LAYERS_ 8

// ws layout (floats) — proven range
#define WS_QKV 0          // [3072]
#define WS_GU 3072        // [8192]
#define WS_HID 11264      // [1024]
#define WS_PART 12288     // [16*65*66 = 68640], ends 80928

static constexpr float SCALE_ = 0.49497474683058327f; // 1.4/sqrt(8)
static constexpr float EPS_ = 1e-5f;

__device__ __forceinline__ float wave_sum(float v) {
    #pragma unroll
    for (int off = 32; off; off >>= 1) v += __shfl_down(v, off, 64);
    return v;
}
__device__ __forceinline__ float wave_max(float v) {
    #pragma unroll
    for (int off = 32; off; off >>= 1) v = fmaxf(v, __shfl_down(v, off, 64));
    return v;
}

// rms(hid)*lnw -> hn[1024]
__device__ __forceinline__ void rms_to_sm(const float* __restrict__ hid,
                                          const float* __restrict__ lnw,
                                          float* hn, float* wred, int t)
{
    float4 hv = ((const float4*)hid)[t];
    float ssq = hv.x*hv.x + hv.y*hv.y + hv.z*hv.z + hv.w*hv.w;
    ssq = wave_sum(ssq);
    if ((t & 63) == 0) wred[t >> 6] = ssq;
    __syncthreads();
    float rms = rsqrtf((wred[0] + wred[1] + wred[2] + wred[3]) * (1.0f / D_) + EPS_);
    float4 lw = ((const float4*)lnw)[t];
    hn[4*t+0] = hv.x * rms * lw.x;
    hn[4*t+1] = hv.y * rms * lw.y;
    hn[4*t+2] = hv.z * rms * lw.z;
    hn[4*t+3] = hv.w * rms * lw.w;
    __syncthreads();
}

// RT-row x 64-col gemv tile: dst[colbase..+64) += scale * (hsrc[rows] @ W-tile)
template<int RT>
__device__ __forceinline__ void gemv_tile(const float* __restrict__ hsrc,
                                          const float* __restrict__ W, int ncols,
                                          int rowbase, int colbase, float scale,
                                          float* __restrict__ dst, float4* red4, int t)
{
    constexpr int RPG = RT / 16;
    int c4 = t & 15, rg = t >> 4;
    int row0 = rowbase + rg * RPG;
    const float* Wp = W + (size_t)row0 * ncols + colbase + c4 * 4;
    float4 acc = make_float4(0.f, 0.f, 0.f, 0.f);
    #pragma unroll
    for (int r = 0; r < RPG; ++r) {
        float hs = hsrc[row0 + r];
        float4 w4 = *(const float4*)(Wp + (size_t)r * ncols);
        acc.x += hs*w4.x; acc.y += hs*w4.y; acc.z += hs*w4.z; acc.w += hs*w4.w;
    }
    red4[t] = acc;
    __syncthreads();
    if (t < 16) {
        float4 s = red4[t];
        #pragma unroll
        for (int g = 1; g < 16; ++g) {
            float4 r4 = red4[t + 16*g];
            s.x += r4.x; s.y += r4.y; s.z += r4.z; s.w += r4.w;
        }
        float* d = dst + colbase + t*4;
        atomicAdd(d+0, scale*s.x);
        atomicAdd(d+1, scale*s.y);
        atomicAdd(d+2, scale*s.z);
        atomicAdd(d+3, scale*s.w);
    }
    __syncthreads();
}

__global__ void k_init(const float* __restrict__ embed, float* __restrict__ hid,
                       float* __restrict__ accQKV) {
    int t = threadIdx.x;
    ((float4*)hid)[t] = ((const float4*)embed)[t];
    for (int i = t; i < 3072; i += 256) accQKV[i] = 0.f;
}

template<int NCOLS>
__global__ void k_rms_gemv(const float* __restrict__ hidden, const float* __restrict__ lnw,
                           const float* __restrict__ W0, const float* __restrict__ W1,
                           const float* __restrict__ W2, float* __restrict__ out)
{
    int t = threadIdx.x;
    __shared__ float hn[D_];
    __shared__ float wred[4];
    __shared__ float4 red4s[256];
    rms_to_sm(hidden, lnw, hn, wred, t);
    const float* W = (blockIdx.z == 0) ? W0 : (blockIdx.z == 1 ? W1 : W2);
    gemv_tile<64>(hn, W, NCOLS, blockIdx.y*64, blockIdx.x*64, 1.f,
                  out + (size_t)blockIdx.z * NCOLS, red4s, t);
}

// flash-decode chunk (64 keys): grid (NCH_, H_); block 256. Fully float4.
// Writes f32 K/V cache output copies (rows < T from f32 cache, row T = roped k / new v).
__global__ void k_attn_f(const float* __restrict__ kcache, const float* __restrict__ vcache,
                         const float* __restrict__ qkv, const int* __restrict__ posp,
                         float* __restrict__ kc_out, float* __restrict__ vc_out,
                         float* __restrict__ part)
{
    int c = blockIdx.x, h = blockIdx.y, t = threadIdx.x;
    __shared__ float qr[64], kr[64], sc[CHUNK_], wr2[8];
    __shared__ float4 red4[256];
    if (t < 32) {
        float pos = (float)(*posp);
        float inv = expf(-(float)t * (9.210340371976184f / 32.0f)); // 10000^(-t/32)
        float ang = pos * inv;
        float cs = cosf(ang), sn = sinf(ang);
        float q1 = qkv[h*64 + t], q2 = qkv[h*64 + t + 32];
        qr[t] = q1*cs - q2*sn; qr[t+32] = q1*sn + q2*cs;
        float k1 = qkv[1024 + h*64 + t], k2 = qkv[1024 + h*64 + t + 32];
        kr[t] = k1*cs - k2*sn; kr[t+32] = k1*sn + k2*cs;
    }
    __syncthreads();
    int kstart = c * CHUNK_;
    int nk = min(CHUNK_, TC_ - kstart);
    // pass A: scores (16 lanes/key, float4) + f32 K copy
    int dsub = (t & 15) * 4;
    float4 qv = *(const float4*)&qr[dsub];
    for (int kl = (t >> 4); kl < nk; kl += 16) {
        int key = kstart + kl;
        float4 kv;
        if (key < T_) kv = *(const float4*)(kcache + ((size_t)h*T_ + key)*HD_ + dsub);
        else          kv = *(const float4*)&kr[dsub];
        float pd = qv.x*kv.x + qv.y*kv.y + qv.z*kv.z + qv.w*kv.w;
        pd += __shfl_down(pd, 8, 16);
        pd += __shfl_down(pd, 4, 16);
        pd += __shfl_down(pd, 2, 16);
        pd += __shfl_down(pd, 1, 16);
        if ((t & 15) == 0) sc[kl] = pd * 0.125f;
        *(float4*)(kc_out + ((size_t)h*TC_ + key)*HD_ + dsub) = kv;
    }
    __syncthreads();
    // parallel chunk softmax (nk <= 64)
    float m = (t < nk) ? sc[t] : -INFINITY;
    m = wave_max(m);
    if ((t & 63) == 0) wr2[t >> 6] = m;
    __syncthreads();
    m = fmaxf(fmaxf(wr2[0], wr2[1]), fmaxf(wr2[2], wr2[3]));
    float e = 0.f;
    if (t < nk) { e = __expf(sc[t] - m); sc[t] = e; }
    float s = wave_sum(e);
    if ((t & 63) == 0) wr2[4 + (t >> 6)] = s;
    __syncthreads();
    float* pb = part + ((size_t)h*NCH_ + c)*66;
    if (t == 0) { pb[0] = m; pb[1] = wr2[4]+wr2[5]+wr2[6]+wr2[7]; }
    __syncthreads();
    // pass B: weighted V, float4 (16 dim-groups x 16 key-groups of 4 keys) + f32 V copy
    int d4 = (t & 15) * 4, kg = t >> 4;
    float4 acc = make_float4(0.f, 0.f, 0.f, 0.f);
    int kl0 = kg * 4, klend = min(nk, kl0 + 4);
    for (int kl = kl0; kl < klend; ++kl) {
        int key = kstart + kl;
        float4 v;
        if (key < T_) v = *(const float4*)(vcache + ((size_t)h*T_ + key)*HD_ + d4);
        else          v = *(const float4*)(qkv + 2048 + h*64 + d4);
        float w = sc[kl];
        acc.x += w*v.x; acc.y += w*v.y; acc.z += w*v.z; acc.w += w*v.w;
        *(float4*)(vc_out + ((size_t)h*TC_ + key)*HD_ + d4) = v;
    }
    red4[t] = acc;
    __syncthreads();
    if (t < 16) {
        float4 s4 = red4[t];
        #pragma unroll
        for (int g = 1; g < 16; ++g) {
            float4 r4 = red4[t + 16*g];
            s4.x += r4.x; s4.y += r4.y; s4.z += r4.z; s4.w += r4.w;
        }
        pb[2 + t*4 + 0] = s4.x;
        pb[2 + t*4 + 1] = s4.y;
        pb[2 + t*4 + 2] = s4.z;
        pb[2 + t*4 + 3] = s4.w;
    }
}

// combine (per-head) + gemv 64 rows of Wo; hidden += SCALE*partial. grid (16,16).
// Block (0,0) zeroes accGU (runs after down(L-1) consumed it).
__global__ void k_wo(const float* __restrict__ part, const float* __restrict__ Wo,
                     float* __restrict__ hidden, float* __restrict__ accGU)
{
    int h = blockIdx.y, t = threadIdx.x;
    if (blockIdx.x == 0 && blockIdx.y == 0)
        for (int i = t; i < 2*FF_; i += 256) accGU[i] = 0.f;
    __shared__ float oh[64];
    __shared__ float4 red4s[256];
    if (t < 64) {
        const float* pb = part + (size_t)h * NCH_ * 66;
        float M = -INFINITY;
        for (int c = 0; c < NCH_; ++c) M = fmaxf(M, pb[c*66]);
        float S = 0.f, O = 0.f;
        for (int c = 0; c < NCH_; ++c) {
            float e = __expf(pb[c*66] - M);
            S += pb[c*66 + 1] * e;
            O += pb[c*66 + 2 + t] * e;
        }
        oh[t] = O / S;
    }
    __syncthreads();
    gemv_tile<64>(oh - h*64, Wo, D_, h*64, blockIdx.x*64, SCALE_, hidden, red4s, t);
}

// hidden += SCALE * (silu(g)*u) @ Wd ; grid (16, 64). Block (0,0) zeroes accQKV.
__global__ void k_down(const float* __restrict__ gu, const float* __restrict__ Wd,
                       float* __restrict__ hidden, float* __restrict__ accQKV)
{
    int t = threadIdx.x;
    if (blockIdx.x == 0 && blockIdx.y == 0)
        for (int i = t; i < 3072; i += 256) accQKV[i] = 0.f;
    __shared__ float act[64];
    __shared__ float4 red4s[256];
    int rowbase = blockIdx.y * 64;
    if (t < 64) {
        float g = gu[rowbase + t];
        float u = gu[FF_ + rowbase + t];
        act[t] = g / (1.f + __expf(-g)) * u;
    }
    __syncthreads();
    gemv_tile<64>(act - rowbase, Wd, D_, rowbase, blockIdx.x*64, SCALE_, hidden, red4s, t);
}

__global__ void k_final(const float* __restrict__ hidden, const float* __restrict__ nw,
                        float* __restrict__ out)
{
    int t = threadIdx.x;
    __shared__ float wred[4];
    float4 hv = ((const float4*)hidden)[t];
    float ssq = hv.x*hv.x + hv.y*hv.y + hv.z*hv.z + hv.w*hv.w;
    ssq = wave_sum(ssq);
    if ((t & 63) == 0) wred[t >> 6] = ssq;
    __syncthreads();
    float rms = rsqrtf((wred[0] + wred[1] + wred[2] + wred[3]) * (1.0f / D_) + EPS_);
    float4 w = ((const float4*)nw)[t];
    float4 ob;
    ob.x = hv.x * rms * w.x; ob.y = hv.y * rms * w.y;
    ob.z = hv.z * rms * w.z; ob.w = hv.w * rms * w.w;
    ((float4*)out)[t] = ob;
}

// role indices: 0 embed, 1+2i k_i, 2+2i v_i, 17 ln1, 18 ln2, 19 norm,
//               20 Wq, 21 Wk, 22 Wv, 23 Wo, 24 Wg, 25 Wu, 26 Wd, 27 pos
static const int ROLE_SIZES[28] = {
    1024,
    4194304,4194304,4194304,4194304,4194304,4194304,4194304,4194304,
    4194304,4194304,4194304,4194304,4194304,4194304,4194304,4194304,
    8192, 8192, 1024,
    8388608, 8388608, 8388608, 8388608,
    33554432, 33554432, 33554432,
    1
};

extern "C" void kernel_launch(void* const* d_in, const int* in_sizes, int n_in,
                              void* d_out, int out_size, void* d_ws, size_t ws_size,
                              hipStream_t stream)
{
    int perm[28];
    bool matched = false;
    auto try_perm = [&](const int* cand) {
        if (matched) return;
        for (int r = 0; r < 28; ++r)
            if (in_sizes[cand[r]] != ROLE_SIZES[r]) return;
        for (int r = 0; r < 28; ++r) perm[r] = cand[r];
        matched = true;
    };
    {   int c[28]; for (int r = 0; r < 28; ++r) c[r] = r; try_perm(c); }  // C0 dict (matched)
    {   int c[28];
        c[0]=0; c[27]=1;
        for (int i = 0; i < 8; ++i) { c[1+2*i]=2+2*i; c[2+2*i]=3+2*i; }
        c[17]=18; c[18]=19; c[19]=20;
        c[20]=21; c[21]=22; c[22]=23; c[23]=24; c[24]=25; c[25]=26; c[26]=27;
        try_perm(c); }                                                    // C1 signature
    if (!matched) { for (int r = 0; r < 28; ++r) perm[r] = r; }

    const float* embed = (const float*)d_in[perm[0]];
    const float* kcs[LAYERS_];
    const float* vcs[LAYERS_];
    for (int i = 0; i < LAYERS_; ++i) {
        kcs[i] = (const float*)d_in[perm[1+2*i]];
        vcs[i] = (const float*)d_in[perm[2+2*i]];
    }
    const float* ln1 = (const float*)d_in[perm[17]];
    const float* ln2 = (const float*)d_in[perm[18]];
    const float* nw  = (const float*)d_in[perm[19]];
    const float* Wq  = (const float*)d_in[perm[20]];
    const float* Wk  = (const float*)d_in[perm[21]];
    const float* Wv  = (const float*)d_in[perm[22]];
    const float* Wo  = (const float*)d_in[perm[23]];
    const float* Wg  = (const float*)d_in[perm[24]];
    const float* Wu  = (const float*)d_in[perm[25]];
    const float* Wd  = (const float*)d_in[perm[26]];
    const int*   pos = (const int*)d_in[perm[27]];

    float* out = (float*)d_out;
    float* ws = (float*)d_ws;
    float* accQKV = ws + WS_QKV;
    float* accGU  = ws + WS_GU;
    float* hid    = ws + WS_HID;
    float* part   = ws + WS_PART;

    (void)out_size; (void)ws_size; (void)n_in;

    k_init<<<1, 256, 0, stream>>>(embed, hid, accQKV);

    const size_t KVSZ = (size_t)H_ * TC_ * HD_; // 4,195,328
    for (int i = 0; i < LAYERS_; ++i) {
        float* kco = out + 1024 + (size_t)i * 2 * KVSZ;
        float* vco = kco + KVSZ;

        k_rms_gemv<D_><<<dim3(16, 16, 3), 256, 0, stream>>>(
            hid, ln1 + i*D_,
            Wq + (size_t)i*D_*D_, Wk + (size_t)i*D_*D_, Wv + (size_t)i*D_*D_,
            accQKV);

        k_attn_f<<<dim3(NCH_, H_), 256, 0, stream>>>(kcs[i], vcs[i], accQKV, pos,
                                                     kco, vco, part);

        k_wo<<<dim3(16, 16), 256, 0, stream>>>(part, Wo + (size_t)i*D_*D_, hid, accGU);

        k_rms_gemv<FF_><<<dim3(64, 16, 2), 256, 0, stream>>>(
            hid, ln2 + i*D_,
            Wg + (size_t)i*D_*FF_, Wu + (size_t)i*D_*FF_, nullptr,
            accGU);

        k_down<<<dim3(16, 64), 256, 0, stream>>>(accGU, Wd + (size_t)i*FF_*D_, hid, accQKV);
    }
    k_final<<<1, 256, 0, stream>>>(hid, nw, out);
}

// Round 11
// 418.048 us; speedup vs baseline: 27.6018x; 1.1317x over previous
//
#include <hip/hip_runtime.h>
#include <stdint.h>

#define D_ 1024
#define H_ 16
#define HD_ 64
#define FF_ 4096
#define T_ 4096
#define TC_ 4097
#define CHUNK_ 128
#define NCH_ 33
#define LAYERS_ 8

// ws layout (floats) — proven range
#define WS_QKV 0          // [3072]
#define WS_GU 3072        // [8192]
#define WS_HID 11264      // [1024]
#define WS_PART 12288     // [16*33*66 = 34848]

static constexpr float SCALE_ = 0.49497474683058327f; // 1.4/sqrt(8)
static constexpr float EPS_ = 1e-5f;

typedef float nf4 __attribute__((ext_vector_type(4)));   // native vec for NT builtins

__device__ __forceinline__ float wave_sum(float v) {
    #pragma unroll
    for (int off = 32; off; off >>= 1) v += __shfl_down(v, off, 64);
    return v;
}
__device__ __forceinline__ float wave_max(float v) {
    #pragma unroll
    for (int off = 32; off; off >>= 1) v = fmaxf(v, __shfl_down(v, off, 64));
    return v;
}

// rms(hid)*lnw -> hn[1024]
__device__ __forceinline__ void rms_to_sm(const float* __restrict__ hid,
                                          const float* __restrict__ lnw,
                                          float* hn, float* wred, int t)
{
    float4 hv = ((const float4*)hid)[t];
    float ssq = hv.x*hv.x + hv.y*hv.y + hv.z*hv.z + hv.w*hv.w;
    ssq = wave_sum(ssq);
    if ((t & 63) == 0) wred[t >> 6] = ssq;
    __syncthreads();
    float rms = rsqrtf((wred[0] + wred[1] + wred[2] + wred[3]) * (1.0f / D_) + EPS_);
    float4 lw = ((const float4*)lnw)[t];
    hn[4*t+0] = hv.x * rms * lw.x;
    hn[4*t+1] = hv.y * rms * lw.y;
    hn[4*t+2] = hv.z * rms * lw.z;
    hn[4*t+3] = hv.w * rms * lw.w;
    __syncthreads();
}

// RT-row x 64-col gemv tile: dst[colbase..+64) += scale * (hsrc[rows] @ W-tile)
template<int RT>
__device__ __forceinline__ void gemv_tile(const float* __restrict__ hsrc,
                                          const float* __restrict__ W, int ncols,
                                          int rowbase, int colbase, float scale,
                                          float* __restrict__ dst, float4* red4, int t)
{
    constexpr int RPG = RT / 16;
    int c4 = t & 15, rg = t >> 4;
    int row0 = rowbase + rg * RPG;
    const float* Wp = W + (size_t)row0 * ncols + colbase + c4 * 4;
    float4 acc = make_float4(0.f, 0.f, 0.f, 0.f);
    #pragma unroll
    for (int r = 0; r < RPG; ++r) {
        float hs = hsrc[row0 + r];
        float4 w4 = *(const float4*)(Wp + (size_t)r * ncols);
        acc.x += hs*w4.x; acc.y += hs*w4.y; acc.z += hs*w4.z; acc.w += hs*w4.w;
    }
    red4[t] = acc;
    __syncthreads();
    if (t < 16) {
        float4 s = red4[t];
        #pragma unroll
        for (int g = 1; g < 16; ++g) {
            float4 r4 = red4[t + 16*g];
            s.x += r4.x; s.y += r4.y; s.z += r4.z; s.w += r4.w;
        }
        float* d = dst + colbase + t*4;
        atomicAdd(d+0, scale*s.x);
        atomicAdd(d+1, scale*s.y);
        atomicAdd(d+2, scale*s.z);
        atomicAdd(d+3, scale*s.w);
    }
    __syncthreads();
}

__global__ void k_init(const float* __restrict__ embed, float* __restrict__ hid,
                       float* __restrict__ accQKV) {
    int t = threadIdx.x;
    ((float4*)hid)[t] = ((const float4*)embed)[t];
    for (int i = t; i < 3072; i += 256) accQKV[i] = 0.f;
}

template<int NCOLS>
__global__ void k_rms_gemv(const float* __restrict__ hidden, const float* __restrict__ lnw,
                           const float* __restrict__ W0, const float* __restrict__ W1,
                           const float* __restrict__ W2, float* __restrict__ out)
{
    int t = threadIdx.x;
    __shared__ float hn[D_];
    __shared__ float wred[4];
    __shared__ float4 red4s[256];
    rms_to_sm(hidden, lnw, hn, wred, t);
    const float* W = (blockIdx.z == 0) ? W0 : (blockIdx.z == 1 ? W1 : W2);
    gemv_tile<64>(hn, W, NCOLS, blockIdx.y*64, blockIdx.x*64, 1.f,
                  out + (size_t)blockIdx.z * NCOLS, red4s, t);
}

// flash-decode chunk (128 keys): grid (NCH_, H_); block 256.
// V prefetched into registers before softmax (latency hidden under pass A + softmax).
// Non-temporal loads/stores (native vec type) for stream-once KV read + f32 copy-out.
__global__ void k_attn_f(const float* __restrict__ kcache, const float* __restrict__ vcache,
                         const float* __restrict__ qkv, const int* __restrict__ posp,
                         float* __restrict__ kc_out, float* __restrict__ vc_out,
                         float* __restrict__ part)
{
    int c = blockIdx.x, h = blockIdx.y, t = threadIdx.x;
    __shared__ float qr[64], kr[64], sc[CHUNK_], wr2[8];
    __shared__ float4 red4[256];
    if (t < 32) {
        float pos = (float)(*posp);
        float inv = expf(-(float)t * (9.210340371976184f / 32.0f)); // 10000^(-t/32)
        float ang = pos * inv;
        float cs = cosf(ang), sn = sinf(ang);
        float q1 = qkv[h*64 + t], q2 = qkv[h*64 + t + 32];
        qr[t] = q1*cs - q2*sn; qr[t+32] = q1*sn + q2*cs;
        float k1 = qkv[1024 + h*64 + t], k2 = qkv[1024 + h*64 + t + 32];
        kr[t] = k1*cs - k2*sn; kr[t+32] = k1*sn + k2*cs;
    }

    int kstart = c * CHUNK_;
    int nk = min(CHUNK_, TC_ - kstart);
    int d4 = (t & 15) * 4;      // column group (16 x 4 dims)
    int kl0 = t >> 4;           // key lane base; keys kl0 + 16j, j=0..7

    // ---- prefetch V into registers (issued before K-dot + softmax) ----
    nf4 vreg[CHUNK_ / 16];
    #pragma unroll
    for (int j = 0; j < CHUNK_ / 16; ++j) {
        int kl = kl0 + 16 * j;
        if (kl < nk) {
            int key = kstart + kl;
            if (key < T_)
                vreg[j] = __builtin_nontemporal_load((const nf4*)(vcache + ((size_t)h*T_ + key)*HD_ + d4));
            else
                vreg[j] = *(const nf4*)(qkv + 2048 + h*64 + d4);
        }
    }

    __syncthreads();   // qr/kr ready
    // ---- pass A: scores (16 lanes/key, float4) + NT K copy ----
    nf4 qv = *(const nf4*)&qr[d4];
    #pragma unroll
    for (int j = 0; j < CHUNK_ / 16; ++j) {
        int kl = kl0 + 16 * j;
        if (kl < nk) {
            int key = kstart + kl;
            nf4 kv;
            if (key < T_) kv = __builtin_nontemporal_load((const nf4*)(kcache + ((size_t)h*T_ + key)*HD_ + d4));
            else          kv = *(const nf4*)&kr[d4];
            float pd = qv.x*kv.x + qv.y*kv.y + qv.z*kv.z + qv.w*kv.w;
            pd += __shfl_down(pd, 8, 16);
            pd += __shfl_down(pd, 4, 16);
            pd += __shfl_down(pd, 2, 16);
            pd += __shfl_down(pd, 1, 16);
            if ((t & 15) == 0) sc[kl] = pd * 0.125f;
            __builtin_nontemporal_store(kv, (nf4*)(kc_out + ((size_t)h*TC_ + key)*HD_ + d4));
        }
    }
    // ---- NT V copy (from regs, overlaps softmax issue) ----
    #pragma unroll
    for (int j = 0; j < CHUNK_ / 16; ++j) {
        int kl = kl0 + 16 * j;
        if (kl < nk) {
            int key = kstart + kl;
            __builtin_nontemporal_store(vreg[j], (nf4*)(vc_out + ((size_t)h*TC_ + key)*HD_ + d4));
        }
    }
    __syncthreads();
    // ---- parallel chunk softmax (nk <= 128 <= 256) ----
    float m = (t < nk) ? sc[t] : -INFINITY;
    m = wave_max(m);
    if ((t & 63) == 0) wr2[t >> 6] = m;
    __syncthreads();
    m = fmaxf(fmaxf(wr2[0], wr2[1]), fmaxf(wr2[2], wr2[3]));
    float e = 0.f;
    if (t < nk) { e = __expf(sc[t] - m); sc[t] = e; }
    float s = wave_sum(e);
    if ((t & 63) == 0) wr2[4 + (t >> 6)] = s;
    __syncthreads();
    float* pb = part + ((size_t)h*NCH_ + c)*66;
    if (t == 0) { pb[0] = m; pb[1] = wr2[4]+wr2[5]+wr2[6]+wr2[7]; }
    __syncthreads();
    // ---- pass B: weighted V from registers ----
    float4 acc = make_float4(0.f, 0.f, 0.f, 0.f);
    #pragma unroll
    for (int j = 0; j < CHUNK_ / 16; ++j) {
        int kl = kl0 + 16 * j;
        if (kl < nk) {
            float w = sc[kl];
            acc.x += w*vreg[j].x; acc.y += w*vreg[j].y;
            acc.z += w*vreg[j].z; acc.w += w*vreg[j].w;
        }
    }
    red4[t] = acc;
    __syncthreads();
    if (t < 16) {
        float4 s4 = red4[t];
        #pragma unroll
        for (int g = 1; g < 16; ++g) {
            float4 r4 = red4[t + 16*g];
            s4.x += r4.x; s4.y += r4.y; s4.z += r4.z; s4.w += r4.w;
        }
        pb[2 + t*4 + 0] = s4.x;
        pb[2 + t*4 + 1] = s4.y;
        pb[2 + t*4 + 2] = s4.z;
        pb[2 + t*4 + 3] = s4.w;
    }
}

// combine (per-head) + gemv 64 rows of Wo; hidden += SCALE*partial. grid (16,16).
// Block (0,0) zeroes accGU.
__global__ void k_wo(const float* __restrict__ part, const float* __restrict__ Wo,
                     float* __restrict__ hidden, float* __restrict__ accGU)
{
    int h = blockIdx.y, t = threadIdx.x;
    if (blockIdx.x == 0 && blockIdx.y == 0)
        for (int i = t; i < 2*FF_; i += 256) accGU[i] = 0.f;
    __shared__ float oh[64];
    __shared__ float4 red4s[256];
    if (t < 64) {
        const float* pb = part + (size_t)h * NCH_ * 66;
        float M = -INFINITY;
        for (int c = 0; c < NCH_; ++c) M = fmaxf(M, pb[c*66]);
        float S = 0.f, O = 0.f;
        for (int c = 0; c < NCH_; ++c) {
            float e = __expf(pb[c*66] - M);
            S += pb[c*66 + 1] * e;
            O += pb[c*66 + 2 + t] * e;
        }
        oh[t] = O / S;
    }
    __syncthreads();
    gemv_tile<64>(oh - h*64, Wo, D_, h*64, blockIdx.x*64, SCALE_, hidden, red4s, t);
}

// hidden += SCALE * (silu(g)*u) @ Wd ; grid (16, 64). Block (0,0) zeroes accQKV.
__global__ void k_down(const float* __restrict__ gu, const float* __restrict__ Wd,
                       float* __restrict__ hidden, float* __restrict__ accQKV)
{
    int t = threadIdx.x;
    if (blockIdx.x == 0 && blockIdx.y == 0)
        for (int i = t; i < 3072; i += 256) accQKV[i] = 0.f;
    __shared__ float act[64];
    __shared__ float4 red4s[256];
    int rowbase = blockIdx.y * 64;
    if (t < 64) {
        float g = gu[rowbase + t];
        float u = gu[FF_ + rowbase + t];
        act[t] = g / (1.f + __expf(-g)) * u;
    }
    __syncthreads();
    gemv_tile<64>(act - rowbase, Wd, D_, rowbase, blockIdx.x*64, SCALE_, hidden, red4s, t);
}

__global__ void k_final(const float* __restrict__ hidden, const float* __restrict__ nw,
                        float* __restrict__ out)
{
    int t = threadIdx.x;
    __shared__ float wred[4];
    float4 hv = ((const float4*)hidden)[t];
    float ssq = hv.x*hv.x + hv.y*hv.y + hv.z*hv.z + hv.w*hv.w;
    ssq = wave_sum(ssq);
    if ((t & 63) == 0) wred[t >> 6] = ssq;
    __syncthreads();
    float rms = rsqrtf((wred[0] + wred[1] + wred[2] + wred[3]) * (1.0f / D_) + EPS_);
    float4 w = ((const float4*)nw)[t];
    float4 ob;
    ob.x = hv.x * rms * w.x; ob.y = hv.y * rms * w.y;
    ob.z = hv.z * rms * w.z; ob.w = hv.w * rms * w.w;
    ((float4*)out)[t] = ob;
}

// role indices: 0 embed, 1+2i k_i, 2+2i v_i, 17 ln1, 18 ln2, 19 norm,
//               20 Wq, 21 Wk, 22 Wv, 23 Wo, 24 Wg, 25 Wu, 26 Wd, 27 pos
static const int ROLE_SIZES[28] = {
    1024,
    4194304,4194304,4194304,4194304,4194304,4194304,4194304,4194304,
    4194304,4194304,4194304,4194304,4194304,4194304,4194304,4194304,
    8192, 8192, 1024,
    8388608, 8388608, 8388608, 8388608,
    33554432, 33554432, 33554432,
    1
};

extern "C" void kernel_launch(void* const* d_in, const int* in_sizes, int n_in,
                              void* d_out, int out_size, void* d_ws, size_t ws_size,
                              hipStream_t stream)
{
    int perm[28];
    bool matched = false;
    auto try_perm = [&](const int* cand) {
        if (matched) return;
        for (int r = 0; r < 28; ++r)
            if (in_sizes[cand[r]] != ROLE_SIZES[r]) return;
        for (int r = 0; r < 28; ++r) perm[r] = cand[r];
        matched = true;
    };
    {   int c[28]; for (int r = 0; r < 28; ++r) c[r] = r; try_perm(c); }  // C0 dict (matched)
    {   int c[28];
        c[0]=0; c[27]=1;
        for (int i = 0; i < 8; ++i) { c[1+2*i]=2+2*i; c[2+2*i]=3+2*i; }
        c[17]=18; c[18]=19; c[19]=20;
        c[20]=21; c[21]=22; c[22]=23; c[23]=24; c[24]=25; c[25]=26; c[26]=27;
        try_perm(c); }                                                    // C1 signature
    if (!matched) { for (int r = 0; r < 28; ++r) perm[r] = r; }

    const float* embed = (const float*)d_in[perm[0]];
    const float* kcs[LAYERS_];
    const float* vcs[LAYERS_];
    for (int i = 0; i < LAYERS_; ++i) {
        kcs[i] = (const float*)d_in[perm[1+2*i]];
        vcs[i] = (const float*)d_in[perm[2+2*i]];
    }
    const float* ln1 = (const float*)d_in[perm[17]];
    const float* ln2 = (const float*)d_in[perm[18]];
    const float* nw  = (const float*)d_in[perm[19]];
    const float* Wq  = (const float*)d_in[perm[20]];
    const float* Wk  = (const float*)d_in[perm[21]];
    const float* Wv  = (const float*)d_in[perm[22]];
    const float* Wo  = (const float*)d_in[perm[23]];
    const float* Wg  = (const float*)d_in[perm[24]];
    const float* Wu  = (const float*)d_in[perm[25]];
    const float* Wd  = (const float*)d_in[perm[26]];
    const int*   pos = (const int*)d_in[perm[27]];

    float* out = (float*)d_out;
    float* ws = (float*)d_ws;
    float* accQKV = ws + WS_QKV;
    float* accGU  = ws + WS_GU;
    float* hid    = ws + WS_HID;
    float* part   = ws + WS_PART;

    (void)out_size; (void)ws_size; (void)n_in;

    k_init<<<1, 256, 0, stream>>>(embed, hid, accQKV);

    const size_t KVSZ = (size_t)H_ * TC_ * HD_; // 4,195,328
    for (int i = 0; i < LAYERS_; ++i) {
        float* kco = out + 1024 + (size_t)i * 2 * KVSZ;
        float* vco = kco + KVSZ;

        k_rms_gemv<D_><<<dim3(16, 16, 3), 256, 0, stream>>>(
            hid, ln1 + i*D_,
            Wq + (size_t)i*D_*D_, Wk + (size_t)i*D_*D_, Wv + (size_t)i*D_*D_,
            accQKV);

        k_attn_f<<<dim3(NCH_, H_), 256, 0, stream>>>(kcs[i], vcs[i], accQKV, pos,
                                                     kco, vco, part);

        k_wo<<<dim3(16, 16), 256, 0, stream>>>(part, Wo + (size_t)i*D_*D_, hid, accGU);

        k_rms_gemv<FF_><<<dim3(64, 16, 2), 256, 0, stream>>>(
            hid, ln2 + i*D_,
            Wg + (size_t)i*D_*FF_, Wu + (size_t)i*D_*FF_, nullptr,
            accGU);

        k_down<<<dim3(16, 64), 256, 0, stream>>>(accGU, Wd + (size_t)i*FF_*D_, hid, accQKV);
    }
    k_final<<<1, 256, 0, stream>>>(hid, nw, out);
}

// Round 13
// 373.496 us; speedup vs baseline: 30.8943x; 1.1193x over previous
//
#include <hip/hip_runtime.h>
#include <stdint.h>

#define D_ 1024
#define H_ 16
#define HD_ 64
#define FF_ 4096
#define T_ 4096
#define TC_ 4097
#define CHUNK_ 128
#define NCH_ 32
#define NV_ 9
#define LAYERS_ 8

// ws layout (floats) — proven range
#define WS_QKV 0          // [3072]
#define WS_GU 3072        // [8192]
#define WS_HID 11264      // [1024]
#define WS_PART 12288     // [16*32*66 = 33792]

static constexpr float SCALE_ = 0.49497474683058327f; // 1.4/sqrt(8)
static constexpr float EPS_ = 1e-5f;

typedef float nf4 __attribute__((ext_vector_type(4)));   // native vec for NT builtins

__device__ __forceinline__ float wave_sum(float v) {
    #pragma unroll
    for (int off = 32; off; off >>= 1) v += __shfl_down(v, off, 64);
    return v;
}
__device__ __forceinline__ float wave_max(float v) {
    #pragma unroll
    for (int off = 32; off; off >>= 1) v = fmaxf(v, __shfl_down(v, off, 64));
    return v;
}

// rms(hid)*lnw -> hn[1024]
__device__ __forceinline__ void rms_to_sm(const float* __restrict__ hid,
                                          const float* __restrict__ lnw,
                                          float* hn, float* wred, int t)
{
    float4 hv = ((const float4*)hid)[t];
    float ssq = hv.x*hv.x + hv.y*hv.y + hv.z*hv.z + hv.w*hv.w;
    ssq = wave_sum(ssq);
    if ((t & 63) == 0) wred[t >> 6] = ssq;
    __syncthreads();
    float rms = rsqrtf((wred[0] + wred[1] + wred[2] + wred[3]) * (1.0f / D_) + EPS_);
    float4 lw = ((const float4*)lnw)[t];
    hn[4*t+0] = hv.x * rms * lw.x;
    hn[4*t+1] = hv.y * rms * lw.y;
    hn[4*t+2] = hv.z * rms * lw.z;
    hn[4*t+3] = hv.w * rms * lw.w;
    __syncthreads();
}

// RT-row x 128-col gemv tile: dst[colbase..+128) += scale * (hsrc[rows] @ W-tile)
// 32 col-groups (x4 floats) x 8 row-groups (RT/8 rows each); RT/8 loads in flight/thread.
template<int RT>
__device__ __forceinline__ void gemv_tile(const float* __restrict__ hsrc,
                                          const float* __restrict__ W, int ncols,
                                          int rowbase, int colbase, float scale,
                                          float* __restrict__ dst, float4* red4, int t)
{
    constexpr int RPG = RT / 8;
    int cg = t & 31, rg = t >> 5;
    int row0 = rowbase + rg * RPG;
    const float* Wp = W + (size_t)row0 * ncols + colbase + cg * 4;
    float4 acc = make_float4(0.f, 0.f, 0.f, 0.f);
    #pragma unroll
    for (int r = 0; r < RPG; ++r) {
        float hs = hsrc[row0 + r];
        float4 w4 = *(const float4*)(Wp + (size_t)r * ncols);
        acc.x += hs*w4.x; acc.y += hs*w4.y; acc.z += hs*w4.z; acc.w += hs*w4.w;
    }
    red4[t] = acc;
    __syncthreads();
    if (t < 32) {
        float4 s = red4[t];
        #pragma unroll
        for (int g = 1; g < 8; ++g) {
            float4 r4 = red4[t + 32*g];
            s.x += r4.x; s.y += r4.y; s.z += r4.z; s.w += r4.w;
        }
        float* d = dst + colbase + t*4;
        atomicAdd(d+0, scale*s.x);
        atomicAdd(d+1, scale*s.y);
        atomicAdd(d+2, scale*s.z);
        atomicAdd(d+3, scale*s.w);
    }
    __syncthreads();
}

__global__ void k_init(const float* __restrict__ embed, float* __restrict__ hid,
                       float* __restrict__ accQKV) {
    int t = threadIdx.x;
    ((float4*)hid)[t] = ((const float4*)embed)[t];
    for (int i = t; i < 3072; i += 256) accQKV[i] = 0.f;
}

// grid (NCOLS/128, 1024/RT, nmat)
template<int NCOLS, int RT>
__global__ void k_rms_gemv(const float* __restrict__ hidden, const float* __restrict__ lnw,
                           const float* __restrict__ W0, const float* __restrict__ W1,
                           const float* __restrict__ W2, float* __restrict__ out)
{
    int t = threadIdx.x;
    __shared__ float hn[D_];
    __shared__ float wred[4];
    __shared__ float4 red4s[256];
    rms_to_sm(hidden, lnw, hn, wred, t);
    const float* W = (blockIdx.z == 0) ? W0 : (blockIdx.z == 1 ? W1 : W2);
    gemv_tile<RT>(hn, W, NCOLS, blockIdx.y*RT, blockIdx.x*128, 1.f,
                  out + (size_t)blockIdx.z * NCOLS, red4s, t);
}

// flash-decode chunk: grid (NCH_=32, H_); block 256. Exactly 2 blocks/CU.
// Chunks 0..30: 128 keys; chunk 31: 129 keys (incl. new key at row T).
// V prefetched to regs before softmax; NT loads/stores for stream-once KV + copy-out.
__global__ void k_attn_f(const float* __restrict__ kcache, const float* __restrict__ vcache,
                         const float* __restrict__ qkv, const int* __restrict__ posp,
                         float* __restrict__ kc_out, float* __restrict__ vc_out,
                         float* __restrict__ part)
{
    int c = blockIdx.x, h = blockIdx.y, t = threadIdx.x;
    __shared__ float qr[64], kr[64], sc[132], wr2[8];
    __shared__ float4 red4[256];
    if (t < 32) {
        float pos = (float)(*posp);
        float inv = expf(-(float)t * (9.210340371976184f / 32.0f)); // 10000^(-t/32)
        float ang = pos * inv;
        float cs = cosf(ang), sn = sinf(ang);
        float q1 = qkv[h*64 + t], q2 = qkv[h*64 + t + 32];
        qr[t] = q1*cs - q2*sn; qr[t+32] = q1*sn + q2*cs;
        float k1 = qkv[1024 + h*64 + t], k2 = qkv[1024 + h*64 + t + 32];
        kr[t] = k1*cs - k2*sn; kr[t+32] = k1*sn + k2*cs;
    }

    int kstart = c * CHUNK_;
    int nk = (c == NCH_-1) ? (TC_ - kstart) : CHUNK_;   // 128, last: 129
    int d4 = (t & 15) * 4;      // column group (16 x 4 dims)
    int kl0 = t >> 4;           // key lane base; keys kl0 + 16j

    // ---- prefetch V into registers (issued before K-dot + softmax) ----
    nf4 vreg[NV_];
    #pragma unroll
    for (int j = 0; j < NV_; ++j) {
        int kl = kl0 + 16 * j;
        if (kl < nk) {
            int key = kstart + kl;
            if (key < T_)
                vreg[j] = __builtin_nontemporal_load((const nf4*)(vcache + ((size_t)h*T_ + key)*HD_ + d4));
            else
                vreg[j] = *(const nf4*)(qkv + 2048 + h*64 + d4);
        }
    }

    __syncthreads();   // qr/kr ready
    // ---- pass A: scores (16 lanes/key, float4) + NT K copy ----
    nf4 qv = *(const nf4*)&qr[d4];
    #pragma unroll
    for (int j = 0; j < NV_; ++j) {
        int kl = kl0 + 16 * j;
        if (kl < nk) {
            int key = kstart + kl;
            nf4 kv;
            if (key < T_) kv = __builtin_nontemporal_load((const nf4*)(kcache + ((size_t)h*T_ + key)*HD_ + d4));
            else          kv = *(const nf4*)&kr[d4];
            float pd = qv.x*kv.x + qv.y*kv.y + qv.z*kv.z + qv.w*kv.w;
            pd += __shfl_down(pd, 8, 16);
            pd += __shfl_down(pd, 4, 16);
            pd += __shfl_down(pd, 2, 16);
            pd += __shfl_down(pd, 1, 16);
            if ((t & 15) == 0) sc[kl] = pd * 0.125f;
            __builtin_nontemporal_store(kv, (nf4*)(kc_out + ((size_t)h*TC_ + key)*HD_ + d4));
        }
    }
    // ---- NT V copy (from regs, overlaps softmax issue) ----
    #pragma unroll
    for (int j = 0; j < NV_; ++j) {
        int kl = kl0 + 16 * j;
        if (kl < nk) {
            int key = kstart + kl;
            __builtin_nontemporal_store(vreg[j], (nf4*)(vc_out + ((size_t)h*TC_ + key)*HD_ + d4));
        }
    }
    __syncthreads();
    // ---- parallel chunk softmax (nk <= 129 <= 256) ----
    float m = (t < nk) ? sc[t] : -INFINITY;
    m = wave_max(m);
    if ((t & 63) == 0) wr2[t >> 6] = m;
    __syncthreads();
    m = fmaxf(fmaxf(wr2[0], wr2[1]), fmaxf(wr2[2], wr2[3]));
    float e = 0.f;
    if (t < nk) { e = __expf(sc[t] - m); sc[t] = e; }
    float s = wave_sum(e);
    if ((t & 63) == 0) wr2[4 + (t >> 6)] = s;
    __syncthreads();
    float* pb = part + ((size_t)h*NCH_ + c)*66;
    if (t == 0) { pb[0] = m; pb[1] = wr2[4]+wr2[5]+wr2[6]+wr2[7]; }
    __syncthreads();
    // ---- pass B: weighted V from registers ----
    float4 acc = make_float4(0.f, 0.f, 0.f, 0.f);
    #pragma unroll
    for (int j = 0; j < NV_; ++j) {
        int kl = kl0 + 16 * j;
        if (kl < nk) {
            float w = sc[kl];
            acc.x += w*vreg[j].x; acc.y += w*vreg[j].y;
            acc.z += w*vreg[j].z; acc.w += w*vreg[j].w;
        }
    }
    red4[t] = acc;
    __syncthreads();
    if (t < 16) {
        float4 s4 = red4[t];
        #pragma unroll
        for (int g = 1; g < 16; ++g) {
            float4 r4 = red4[t + 16*g];
            s4.x += r4.x; s4.y += r4.y; s4.z += r4.z; s4.w += r4.w;
        }
        pb[2 + t*4 + 0] = s4.x;
        pb[2 + t*4 + 1] = s4.y;
        pb[2 + t*4 + 2] = s4.z;
        pb[2 + t*4 + 3] = s4.w;
    }
}

// combine (per-head) + gemv 64 rows of Wo; hidden += SCALE*partial. grid (8, 16).
// Block (0,0) zeroes accGU.
__global__ void k_wo(const float* __restrict__ part, const float* __restrict__ Wo,
                     float* __restrict__ hidden, float* __restrict__ accGU)
{
    int h = blockIdx.y, t = threadIdx.x;
    if (blockIdx.x == 0 && blockIdx.y == 0)
        for (int i = t; i < 2*FF_; i += 256) accGU[i] = 0.f;
    __shared__ float oh[64];
    __shared__ float4 red4s[256];
    if (t < 64) {
        const float* pb = part + (size_t)h * NCH_ * 66;
        float M = -INFINITY;
        for (int c = 0; c < NCH_; ++c) M = fmaxf(M, pb[c*66]);
        float S = 0.f, O = 0.f;
        for (int c = 0; c < NCH_; ++c) {
            float e = __expf(pb[c*66] - M);
            S += pb[c*66 + 1] * e;
            O += pb[c*66 + 2 + t] * e;
        }
        oh[t] = O / S;
    }
    __syncthreads();
    gemv_tile<64>(oh - h*64, Wo, D_, h*64, blockIdx.x*128, SCALE_, hidden, red4s, t);
}

// hidden += SCALE * (silu(g)*u) @ Wd ; grid (8, 32): x = coltile(128), y = rowtile(128 of 4096).
// Block (0,0) zeroes accQKV.
__global__ void k_down(const float* __restrict__ gu, const float* __restrict__ Wd,
                       float* __restrict__ hidden, float* __restrict__ accQKV)
{
    int t = threadIdx.x;
    if (blockIdx.x == 0 && blockIdx.y == 0)
        for (int i = t; i < 3072; i += 256) accQKV[i] = 0.f;
    __shared__ float act[128];
    __shared__ float4 red4s[256];
    int rowbase = blockIdx.y * 128;
    if (t < 128) {
        float g = gu[rowbase + t];
        float u = gu[FF_ + rowbase + t];
        act[t] = g / (1.f + __expf(-g)) * u;
    }
    __syncthreads();
    gemv_tile<128>(act - rowbase, Wd, D_, rowbase, blockIdx.x*128, SCALE_, hidden, red4s, t);
}

__global__ void k_final(const float* __restrict__ hidden, const float* __restrict__ nw,
                        float* __restrict__ out)
{
    int t = threadIdx.x;
    __shared__ float wred[4];
    float4 hv = ((const float4*)hidden)[t];
    float ssq = hv.x*hv.x + hv.y*hv.y + hv.z*hv.z + hv.w*hv.w;
    ssq = wave_sum(ssq);
    if ((t & 63) == 0) wred[t >> 6] = ssq;
    __syncthreads();
    float rms = rsqrtf((wred[0] + wred[1] + wred[2] + wred[3]) * (1.0f / D_) + EPS_);
    float4 w = ((const float4*)nw)[t];
    float4 ob;
    ob.x = hv.x * rms * w.x; ob.y = hv.y * rms * w.y;
    ob.z = hv.z * rms * w.z; ob.w = hv.w * rms * w.w;
    ((float4*)out)[t] = ob;
}

// role indices: 0 embed, 1+2i k_i, 2+2i v_i, 17 ln1, 18 ln2, 19 norm,
//               20 Wq, 21 Wk, 22 Wv, 23 Wo, 24 Wg, 25 Wu, 26 Wd, 27 pos
static const int ROLE_SIZES[28] = {
    1024,
    4194304,4194304,4194304,4194304,4194304,4194304,4194304,4194304,
    4194304,4194304,4194304,4194304,4194304,4194304,4194304,4194304,
    8192, 8192, 1024,
    8388608, 8388608, 8388608, 8388608,
    33554432, 33554432, 33554432,
    1
};

extern "C" void kernel_launch(void* const* d_in, const int* in_sizes, int n_in,
                              void* d_out, int out_size, void* d_ws, size_t ws_size,
                              hipStream_t stream)
{
    int perm[28];
    bool matched = false;
    auto try_perm = [&](const int* cand) {
        if (matched) return;
        for (int r = 0; r < 28; ++r)
            if (in_sizes[cand[r]] != ROLE_SIZES[r]) return;
        for (int r = 0; r < 28; ++r) perm[r] = cand[r];
        matched = true;
    };
    {   int c[28]; for (int r = 0; r < 28; ++r) c[r] = r; try_perm(c); }  // C0 dict (matched)
    {   int c[28];
        c[0]=0; c[27]=1;
        for (int i = 0; i < 8; ++i) { c[1+2*i]=2+2*i; c[2+2*i]=3+2*i; }
        c[17]=18; c[18]=19; c[19]=20;
        c[20]=21; c[21]=22; c[22]=23; c[23]=24; c[24]=25; c[25]=26; c[26]=27;
        try_perm(c); }                                                    // C1 signature
    if (!matched) { for (int r = 0; r < 28; ++r) perm[r] = r; }

    const float* embed = (const float*)d_in[perm[0]];
    const float* kcs[LAYERS_];
    const float* vcs[LAYERS_];
    for (int i = 0; i < LAYERS_; ++i) {
        kcs[i] = (const float*)d_in[perm[1+2*i]];
        vcs[i] = (const float*)d_in[perm[2+2*i]];
    }
    const float* ln1 = (const float*)d_in[perm[17]];
    const float* ln2 = (const float*)d_in[perm[18]];
    const float* nw  = (const float*)d_in[perm[19]];
    const float* Wq  = (const float*)d_in[perm[20]];
    const float* Wk  = (const float*)d_in[perm[21]];
    const float* Wv  = (const float*)d_in[perm[22]];
    const float* Wo  = (const float*)d_in[perm[23]];
    const float* Wg  = (const float*)d_in[perm[24]];
    const float* Wu  = (const float*)d_in[perm[25]];
    const float* Wd  = (const float*)d_in[perm[26]];
    const int*   pos = (const int*)d_in[perm[27]];

    float* out = (float*)d_out;
    float* ws = (float*)d_ws;
    float* accQKV = ws + WS_QKV;
    float* accGU  = ws + WS_GU;
    float* hid    = ws + WS_HID;
    float* part   = ws + WS_PART;

    (void)out_size; (void)ws_size; (void)n_in;

    k_init<<<1, 256, 0, stream>>>(embed, hid, accQKV);

    const size_t KVSZ = (size_t)H_ * TC_ * HD_; // 4,195,328
    for (int i = 0; i < LAYERS_; ++i) {
        float* kco = out + 1024 + (size_t)i * 2 * KVSZ;
        float* vco = kco + KVSZ;

        k_rms_gemv<D_, 64><<<dim3(8, 16, 3), 256, 0, stream>>>(
            hid, ln1 + i*D_,
            Wq + (size_t)i*D_*D_, Wk + (size_t)i*D_*D_, Wv + (size_t)i*D_*D_,
            accQKV);

        k_attn_f<<<dim3(NCH_, H_), 256, 0, stream>>>(kcs[i], vcs[i], accQKV, pos,
                                                     kco, vco, part);

        k_wo<<<dim3(8, 16), 256, 0, stream>>>(part, Wo + (size_t)i*D_*D_, hid, accGU);

        k_rms_gemv<FF_, 128><<<dim3(32, 8, 2), 256, 0, stream>>>(
            hid, ln2 + i*D_,
            Wg + (size_t)i*D_*FF_, Wu + (size_t)i*D_*FF_, nullptr,
            accGU);

        k_down<<<dim3(8, 32), 256, 0, stream>>>(accGU, Wd + (size_t)i*FF_*D_, hid, accQKV);
    }
    k_final<<<1, 256, 0, stream>>>(hid, nw, out);
}